// Round 14
// baseline (475.869 us; speedup 1.0000x reference)
//
#include <hip/hip_runtime.h>

#define T_SEQ 188
#define NB    256
#define NIN   128
#define NH    256
#define SCQ   (0.0625f / 16129.0f)   // (0.0625/127) * (1/127)

typedef __attribute__((ext_vector_type(8))) short s16x8;
typedef __attribute__((ext_vector_type(4))) short s16x4;
typedef __attribute__((ext_vector_type(4))) float f32x4;
typedef __attribute__((ext_vector_type(4))) int   i32x4;

__device__ __forceinline__ short f2bf(float f) {
    union { float f; unsigned u; } v; v.f = f;
    unsigned r = v.u + 0x7fffu + ((v.u >> 16) & 1u);   // RNE
    return (short)(r >> 16);
}
__device__ __forceinline__ float bf2f(unsigned short s) {
    union { unsigned u; float f; } t; t.u = ((unsigned)s) << 16; return t.f;
}
__device__ __forceinline__ float sigf(float x) {
    return __builtin_amdgcn_rcpf(1.0f + __expf(-x));
}
__device__ __forceinline__ float tanh_(float x) {
    return 1.0f - 2.0f * __builtin_amdgcn_rcpf(__expf(2.0f * x) + 1.0f);
}

// LDS-only barrier: drain own LDS ops, then workgroup barrier (no vmcnt drain).
__device__ __forceinline__ void lds_barrier() {
    asm volatile("s_waitcnt lgkmcnt(0)" ::: "memory");
    __builtin_amdgcn_s_barrier();
    asm volatile("" ::: "memory");
}

// ================= Phase 1: xp[d][t][b][g] = x[t]·W_ih_d^T + b_ih + b_hh (bf16) =====
__global__ __launch_bounds__(256) void xp_gemm(
    const float* __restrict__ x,
    const float* __restrict__ w_ih_f, const float* __restrict__ w_ih_b,
    const float* __restrict__ b_ih_f, const float* __restrict__ b_hh_f,
    const float* __restrict__ b_ih_b, const float* __restrict__ b_hh_b,
    unsigned short* __restrict__ xp)
{
    const int mt = blockIdx.x >> 5;
    const int dn = blockIdx.x & 31;
    const int d  = dn >> 4, nt = dn & 15;
    const int t  = mt >> 2, b0 = (mt & 3) * 64, Nb = nt * 64;
    const float* w_ih = d ? w_ih_b : w_ih_f;
    const float* b_ih = d ? b_ih_b : b_ih_f;
    const float* b_hh = d ? b_hh_b : b_hh_f;
    const int tid = threadIdx.x;

    __shared__ short xl[64][136];
    __shared__ short wl[64][136];

    #pragma unroll
    for (int j = 0; j < 8; ++j) {
        const int c2 = tid + j * 256;
        const int r = c2 >> 5, o4 = (c2 & 31) * 4;
        float4 xv = *(const float4*)(x + ((size_t)(t * NB + b0 + r)) * NIN + o4);
        s16x4 xs; xs[0] = f2bf(xv.x); xs[1] = f2bf(xv.y); xs[2] = f2bf(xv.z); xs[3] = f2bf(xv.w);
        *(s16x4*)&xl[r][o4] = xs;
        float4 wv = *(const float4*)(w_ih + ((size_t)(Nb + r)) * NIN + o4);
        s16x4 ws_; ws_[0] = f2bf(wv.x); ws_[1] = f2bf(wv.y); ws_[2] = f2bf(wv.z); ws_[3] = f2bf(wv.w);
        *(s16x4*)&wl[r][o4] = ws_;
    }
    __syncthreads();

    const int v = tid >> 6, l = tid & 63, lg = l >> 4, lb = l & 15;
    s16x8 a[4];
    #pragma unroll
    for (int kk = 0; kk < 4; ++kk)
        a[kk] = *(const s16x8*)&xl[16 * v + lb][kk * 32 + 8 * lg];
    f32x4 acc[4];
    #pragma unroll
    for (int nf = 0; nf < 4; ++nf) {
        const int g = Nb + nf * 16 + lb;
        const float bs = b_ih[g] + b_hh[g];
        acc[nf][0] = bs; acc[nf][1] = bs; acc[nf][2] = bs; acc[nf][3] = bs;
    }
    #pragma unroll
    for (int kk = 0; kk < 4; ++kk)
        #pragma unroll
        for (int nf = 0; nf < 4; ++nf) {
            s16x8 bf_ = *(const s16x8*)&wl[nf * 16 + lb][kk * 32 + 8 * lg];
            acc[nf] = __builtin_amdgcn_mfma_f32_16x16x32_bf16(a[kk], bf_, acc[nf], 0, 0, 0);
        }
    #pragma unroll
    for (int nf = 0; nf < 4; ++nf)
        #pragma unroll
        for (int rr = 0; rr < 4; ++rr) {
            const int b = b0 + 16 * v + 4 * lg + rr;
            xp[((size_t)(d * T_SEQ + t) * NB + b) * 1024 + Nb + nf * 16 + lb] =
                (unsigned short)f2bf(acc[nf][rr]);
        }
}

// ================= Phase 2: recurrence, 2-chain software pipeline ==================
// Grid 128 = 2 dirs * 64 batch-tiles (4 rows), block 1024 (16 waves, 4 w/SIMD).
// Chains: A = batch cols {0,1}, B = {2,3} — independent recurrences, shared wq.
// Per phase: ALL waves run 16 MFMAs for one chain while the other chain's gate
// waves (8 of 16; 2/SIMD) run transcendentals -> MFMA & trans pipes overlap.
// hl linear B-layout (R13): byte(k,col) = (k>>6)*1024 + ((k>>4)&3)*256 + col*16 + (k&15).
// rscr[G*2+c'][hu] i32: writes b128 2-way, reads b32 2-way (free, m136).
__device__ __forceinline__ void mfma_phase(
    const int* buf, int (*rs)[256], int cb,
    int w, int l, int lg, int lb, const i32x4 (&wq)[4][4])
{
    i32x4 ac[4];
    #pragma unroll
    for (int G = 0; G < 4; ++G) { ac[G][0] = 0; ac[G][1] = 0; ac[G][2] = 0; ac[G][3] = 0; }
    #pragma unroll
    for (int kk = 0; kk < 4; ++kk) {
        i32x4 bq = *(const i32x4*)&buf[kk * 256 + 4 * l];
        ac[0] = __builtin_amdgcn_mfma_i32_16x16x64_i8(wq[0][kk], bq, ac[0], 0, 0, 0);
        ac[1] = __builtin_amdgcn_mfma_i32_16x16x64_i8(wq[1][kk], bq, ac[1], 0, 0, 0);
        ac[2] = __builtin_amdgcn_mfma_i32_16x16x64_i8(wq[2][kk], bq, ac[2], 0, 0, 0);
        ac[3] = __builtin_amdgcn_mfma_i32_16x16x64_i8(wq[3][kk], bq, ac[3], 0, 0, 0);
    }
    if (lb >= cb && lb < cb + 2) {          // real batch cols of this chain
        const int c1 = lb - cb;
        #pragma unroll
        for (int G = 0; G < 4; ++G)
            *(i32x4*)&rs[G * 2 + c1][16 * w + 4 * lg] = ac[G];   // hu rows 4lg..+3
    }
}

__device__ __forceinline__ void gates_phase(
    const int (*rs)[256], int lq, int hu,
    float& cst, unsigned short (&X)[4],
    const unsigned short*& xpp, long dxp, float*& outp, long dout,
    signed char* hlbyte)
{
    const int a0 = rs[0 + lq][hu];
    const int a1 = rs[2 + lq][hu];
    const int a2 = rs[4 + lq][hu];
    const int a3 = rs[6 + lq][hu];
    const float gi = SCQ * (float)a0 + bf2f(X[0]);
    const float gf = SCQ * (float)a1 + bf2f(X[1]);
    const float gg = SCQ * (float)a2 + bf2f(X[2]);
    const float go = SCQ * (float)a3 + bf2f(X[3]);
    const float iv = sigf(gi), fv = sigf(gf);
    const float gv = tanh_(gg), ov = sigf(go);
    const float cc = fv * cst + iv * gv;
    cst = cc;
    const float h = ov * tanh_(cc);
    *outp = h;
    outp += dout;
    *hlbyte = (signed char)(int)rintf(h * 127.0f);
    // prefetch next step's xp (one full step of latency slack)
    X[0] = xpp[0]; X[1] = xpp[256]; X[2] = xpp[512]; X[3] = xpp[768];
    xpp += dxp;
}

__global__ __launch_bounds__(1024, 4) void lstm_rec(
    const float* __restrict__ w_hh_f, const float* __restrict__ w_hh_b,
    const unsigned short* __restrict__ xp, float* __restrict__ out)
{
    const int bid = blockIdx.x;
    const int d  = bid >> 6;
    const int bt = bid & 63;
    const float* w_hh = d ? w_hh_b : w_hh_f;
    const int tid = threadIdx.x;
    const int w = tid >> 6, l = tid & 63, lg = l >> 4, lb = l & 15;
    const int grp = w >> 3;               // 0: gates of chain A, 1: chain B
    const int gw  = w & 7;
    const int lq  = l & 1;
    const int hu  = 32 * gw + (l >> 1);   // this thread's gate-set hidden unit
    const int c   = 2 * grp + lq;         // this thread's batch col

    __shared__ int hlA[1024], hlB[1024];        // i8 h, linear layout, 4 KB each
    __shared__ int rsA[8][256], rsB[8][256];    // [G*2+c'][hu] raw accs, 8 KB each

    // ---- W_hh -> i8 A-fragments (lane: A[row=lb][k = 64*kk + 16*lg + e]) ----
    i32x4 wq[4][4];
    #pragma unroll
    for (int G = 0; G < 4; ++G) {
        const int row = G * 256 + 16 * w + lb;
        #pragma unroll
        for (int kk = 0; kk < 4; ++kk) {
            i32x4 pk;
            #pragma unroll
            for (int r = 0; r < 4; ++r) {
                float4 wv = *(const float4*)(w_hh + (size_t)row * NH + kk * 64 + 16 * lg + 4 * r);
                const int q0 = (int)rintf(wv.x * 2032.0f) & 255;
                const int q1 = (int)rintf(wv.y * 2032.0f) & 255;
                const int q2 = (int)rintf(wv.z * 2032.0f) & 255;
                const int q3 = (int)rintf(wv.w * 2032.0f) & 255;
                pk[r] = q0 | (q1 << 8) | (q2 << 16) | (q3 << 24);
            }
            wq[G][kk] = pk;
        }
    }
    hlA[tid] = 0; hlB[tid] = 0;   // h(0) = 0 (cols >=4 stay 0 forever)

    // thread-constant addresses
    const int hlw = (hu >> 6) * 1024 + ((hu >> 4) & 3) * 256 + c * 16 + (hu & 15);
    signed char* hlbyte = (signed char*)(grp ? hlB : hlA) + hlw;

    float cst = 0.f;
    unsigned short X[4];
    const int t0 = d ? (T_SEQ - 1) : 0;
    const long dxp  = (d ? -(long)NB : (long)NB) * 1024;
    const long dout = (d ? -(long)NB : (long)NB) * 512;
    const unsigned short* xpp =
        xp + ((size_t)(d * T_SEQ + t0) * NB + bt * 4 + c) * 1024 + hu;
    float* outp = out + ((size_t)t0 * NB + bt * 4 + c) * 512 + d * 256 + hu;
    X[0] = xpp[0]; X[1] = xpp[256]; X[2] = xpp[512]; X[3] = xpp[768];
    xpp += dxp;
    __syncthreads();

    // pipeline prologue: MFMA_A(0) (hlA = 0 -> zero accs, uniform code path)
    mfma_phase(hlA, rsA, 0, w, l, lg, lb, wq);
    lds_barrier();

    for (int s = 0; s < T_SEQ; ++s) {
        // phase: MFMA_B(s)  ||  gates_A(s)  (consumes rsA from previous phase)
        mfma_phase(hlB, rsB, 2, w, l, lg, lb, wq);
        if (grp == 0)
            gates_phase(rsA, lq, hu, cst, X, xpp, dxp, outp, dout, hlbyte);
        lds_barrier();
        // phase: MFMA_A(s+1)  ||  gates_B(s)  (consumes rsB)
        if (s < T_SEQ - 1)
            mfma_phase(hlA, rsA, 0, w, l, lg, lb, wq);
        if (grp == 1)
            gates_phase(rsB, lq, hu, cst, X, xpp, dxp, outp, dout, hlbyte);
        lds_barrier();
    }
}

// ================= Fallback (R3, 829 us): used only if ws too small ================
#define ZSTR_FB 392
__global__ __launch_bounds__(512, 2) void lstm_fb(
    const float* __restrict__ x,
    const float* __restrict__ w_ih_f, const float* __restrict__ w_hh_f,
    const float* __restrict__ b_ih_f, const float* __restrict__ b_hh_f,
    const float* __restrict__ w_ih_b, const float* __restrict__ w_hh_b,
    const float* __restrict__ b_ih_b, const float* __restrict__ b_hh_b,
    float* __restrict__ out, unsigned* __restrict__ flags)
{
    const int b  = blockIdx.x;
    const int d  = b >> 5;
    const int hh = (b >> 4) & 1;
    const int bt = b & 15;
    const int pb = b ^ 16;
    const int po = 1 - hh;
    const float* w_ih = d ? w_ih_b : w_ih_f;
    const float* w_hh = d ? w_hh_b : w_hh_f;
    const float* b_ih = d ? b_ih_b : b_ih_f;
    const float* b_hh = d ? b_hh_b : b_hh_f;
    const int tid = threadIdx.x;
    const int w = tid >> 6, l = tid & 63, lg = l >> 4, lb = l & 15;
    const int hbase = hh * 128 + 16 * w;

    __shared__ short Z[2][16][ZSTR_FB];
    __shared__ float biasL[8][4][16];
    const int off_x   = lg * 8;
    const int off_own = (4 + 4 * hh) * 32 + lg * 8;
    const int off_par = (4 + 4 * po) * 32 + lg * 8;

    s16x8 wf[4][12];
    #pragma unroll
    for (int G = 0; G < 4; ++G) {
        const int gc = G * 256 + hbase + lb;
        #pragma unroll
        for (int kkidx = 0; kkidx < 12; ++kkidx) {
            const int kb = (kkidx < 4) ? (off_x + 32 * kkidx)
                         : (kkidx < 8) ? (off_own + 32 * (kkidx - 4))
                                       : (off_par + 32 * (kkidx - 8));
            const float* src = (kb < NIN) ? (w_ih + (size_t)gc * NIN + kb)
                                          : (w_hh + (size_t)gc * NH + (kb - NIN));
            float4 a  = *(const float4*)(src);
            float4 b2 = *(const float4*)(src + 4);
            s16x8 tv;
            tv[0] = f2bf(a.x);  tv[1] = f2bf(a.y);  tv[2] = f2bf(a.z);  tv[3] = f2bf(a.w);
            tv[4] = f2bf(b2.x); tv[5] = f2bf(b2.y); tv[6] = f2bf(b2.z); tv[7] = f2bf(b2.w);
            wf[G][kkidx] = tv;
        }
    }
    {
        const int G = lb >> 2, r = lb & 3;
        const int gcr = G * 256 + hbase + 4 * lg + r;
        biasL[w][G][4 * lg + r] = b_ih[gcr] + b_hh[gcr];
    }
    const int srow = tid >> 5;
    const int sk4  = (tid & 31) * 4;
    {
        s16x8 zz;
        #pragma unroll
        for (int i = 0; i < 8; ++i) zz[i] = 0;
        *(s16x8*)&Z[0][srow][NIN + (tid & 31) * 8] = zz;
        const int t0 = d ? (T_SEQ - 1) : 0;
        float4 xv0 = *(const float4*)(x + ((size_t)(t0 * NB + bt * 16 + srow)) * NIN + sk4);
        s16x4 xp_;
        xp_[0] = f2bf(xv0.x); xp_[1] = f2bf(xv0.y); xp_[2] = f2bf(xv0.z); xp_[3] = f2bf(xv0.w);
        *(s16x4*)&Z[0][srow][sk4] = xp_;
    }
    float cst[4] = {0.f, 0.f, 0.f, 0.f};
    __syncthreads();
    unsigned* myflag = flags + b * 16;
    unsigned* pflag  = flags + pb * 16;
    float* outp = out + (size_t)(bt * 16) * 512 + d * 256 + hbase + 4 * lg;

    for (int s = 0; s < T_SEQ; ++s) {
        const int p = s & 1;
        const int t = d ? (T_SEQ - 1 - s) : s;
        float4 xv;
        const bool havex = (s + 1 < T_SEQ);
        if (havex) {
            const int tn = d ? (T_SEQ - 2 - s) : (s + 1);
            xv = *(const float4*)(x + ((size_t)(tn * NB + bt * 16 + srow)) * NIN + sk4);
        }
        f32x4 acc[4];
        #pragma unroll
        for (int G = 0; G < 4; ++G)
            acc[G] = *(const f32x4*)&biasL[w][G][4 * lg];
        const short* zrow = &Z[p][lb][0];
        #pragma unroll
        for (int kk = 0; kk < 4; ++kk) {
            s16x8 bfv = *(const s16x8*)(zrow + off_x + 32 * kk);
            acc[0] = __builtin_amdgcn_mfma_f32_16x16x32_bf16(wf[0][kk], bfv, acc[0], 0, 0, 0);
            acc[1] = __builtin_amdgcn_mfma_f32_16x16x32_bf16(wf[1][kk], bfv, acc[1], 0, 0, 0);
            acc[2] = __builtin_amdgcn_mfma_f32_16x16x32_bf16(wf[2][kk], bfv, acc[2], 0, 0, 0);
            acc[3] = __builtin_amdgcn_mfma_f32_16x16x32_bf16(wf[3][kk], bfv, acc[3], 0, 0, 0);
        }
        #pragma unroll
        for (int kk = 0; kk < 4; ++kk) {
            s16x8 bfv = *(const s16x8*)(zrow + off_own + 32 * kk);
            acc[0] = __builtin_amdgcn_mfma_f32_16x16x32_bf16(wf[0][4 + kk], bfv, acc[0], 0, 0, 0);
            acc[1] = __builtin_amdgcn_mfma_f32_16x16x32_bf16(wf[1][4 + kk], bfv, acc[1], 0, 0, 0);
            acc[2] = __builtin_amdgcn_mfma_f32_16x16x32_bf16(wf[2][4 + kk], bfv, acc[2], 0, 0, 0);
            acc[3] = __builtin_amdgcn_mfma_f32_16x16x32_bf16(wf[3][4 + kk], bfv, acc[3], 0, 0, 0);
        }
        if (s > 0) {
            const unsigned want = (unsigned)s;
            while (__hip_atomic_load(pflag, __ATOMIC_RELAXED, __HIP_MEMORY_SCOPE_AGENT) < want)
                __builtin_amdgcn_s_sleep(1);
            __builtin_amdgcn_fence(__ATOMIC_ACQUIRE, "agent");
            const int tprev = d ? (T_SEQ - s) : (s - 1);
            float4 pv = *(const float4*)(out + (size_t)tprev * NB * 512
                         + (size_t)(bt * 16 + srow) * 512 + d * 256 + po * 128 + sk4);
            s16x4 pp;
            pp[0] = f2bf(pv.x); pp[1] = f2bf(pv.y); pp[2] = f2bf(pv.z); pp[3] = f2bf(pv.w);
            *(s16x4*)&Z[p][srow][NIN + po * 128 + sk4] = pp;
        }
        __syncthreads();
        #pragma unroll
        for (int kk = 0; kk < 4; ++kk) {
            s16x8 bfv = *(const s16x8*)(zrow + off_par + 32 * kk);
            acc[0] = __builtin_amdgcn_mfma_f32_16x16x32_bf16(wf[0][8 + kk], bfv, acc[0], 0, 0, 0);
            acc[1] = __builtin_amdgcn_mfma_f32_16x16x32_bf16(wf[1][8 + kk], bfv, acc[1], 0, 0, 0);
            acc[2] = __builtin_amdgcn_mfma_f32_16x16x32_bf16(wf[2][8 + kk], bfv, acc[2], 0, 0, 0);
            acc[3] = __builtin_amdgcn_mfma_f32_16x16x32_bf16(wf[3][8 + kk], bfv, acc[3], 0, 0, 0);
        }
        float4 hout; s16x4 hbf;
        #pragma unroll
        for (int r = 0; r < 4; ++r) {
            const float iv = sigf(acc[0][r]);
            const float fv = sigf(acc[1][r]);
            const float gv = tanh_(acc[2][r]);
            const float ov = sigf(acc[3][r]);
            const float cc = fv * cst[r] + iv * gv;
            cst[r] = cc;
            const float h = ov * tanh_(cc);
            (&hout.x)[r] = h;
            hbf[r] = f2bf(h);
        }
        *(s16x4*)&Z[p ^ 1][lb][NIN + hbase + 4 * lg] = hbf;
        if (havex) {
            s16x4 xp_;
            xp_[0] = f2bf(xv.x); xp_[1] = f2bf(xv.y); xp_[2] = f2bf(xv.z); xp_[3] = f2bf(xv.w);
            *(s16x4*)&Z[p ^ 1][srow][sk4] = xp_;
        }
        *(f32x4*)(outp + (size_t)t * NB * 512 + lb * 512) = *(f32x4*)&hout;
        __syncthreads();
        if (tid == 0 && s + 1 < T_SEQ)
            __hip_atomic_store(myflag, (unsigned)(s + 1),
                               __ATOMIC_RELEASE, __HIP_MEMORY_SCOPE_AGENT);
    }
}

extern "C" void kernel_launch(void* const* d_in, const int* in_sizes, int n_in,
                              void* d_out, int out_size, void* d_ws, size_t ws_size,
                              hipStream_t stream) {
    const float* x      = (const float*)d_in[0];
    const float* w_ih_f = (const float*)d_in[1];
    const float* w_hh_f = (const float*)d_in[2];
    const float* b_ih_f = (const float*)d_in[3];
    const float* b_hh_f = (const float*)d_in[4];
    const float* w_ih_b = (const float*)d_in[5];
    const float* w_hh_b = (const float*)d_in[6];
    const float* b_ih_b = (const float*)d_in[7];
    const float* b_hh_b = (const float*)d_in[8];
    float* out = (float*)d_out;

    const size_t XPN = (size_t)2 * T_SEQ * NB * 1024;   // elements
    const int g1 = (T_SEQ * NB / 64) * 32;              // 24064 WGs

    if (ws_size >= XPN * 2) {
        unsigned short* xp = (unsigned short*)d_ws;
        xp_gemm<<<dim3(g1), dim3(256), 0, stream>>>(
            x, w_ih_f, w_ih_b, b_ih_f, b_hh_f, b_ih_b, b_hh_b, xp);
        lstm_rec<<<dim3(128), dim3(1024), 0, stream>>>(w_hh_f, w_hh_b, xp, out);
    } else {
        unsigned* flags = (unsigned*)d_ws;
        hipMemsetAsync(flags, 0, 4096, stream);
        lstm_fb<<<dim3(64), dim3(512), 0, stream>>>(
            x, w_ih_f, w_hh_f, b_ih_f, b_hh_f, w_ih_b, w_hh_b, b_ih_b, b_hh_b,
            out, flags);
    }
}

// Round 15
// 429.495 us; speedup vs baseline: 1.1080x; 1.1080x over previous
//
#include <hip/hip_runtime.h>

#define T_SEQ 188
#define NB    256
#define NIN   128
#define NH    256
#define SCQ   (0.0625f / 16129.0f)   // (0.0625/127) * (1/127)

typedef __attribute__((ext_vector_type(8))) short s16x8;
typedef __attribute__((ext_vector_type(4))) short s16x4;
typedef __attribute__((ext_vector_type(4))) float f32x4;
typedef __attribute__((ext_vector_type(4))) int   i32x4;

__device__ __forceinline__ short f2bf(float f) {
    union { float f; unsigned u; } v; v.f = f;
    unsigned r = v.u + 0x7fffu + ((v.u >> 16) & 1u);   // RNE
    return (short)(r >> 16);
}
__device__ __forceinline__ float bf2f(unsigned short s) {
    union { unsigned u; float f; } t; t.u = ((unsigned)s) << 16; return t.f;
}
__device__ __forceinline__ float sigf(float x) {
    return __builtin_amdgcn_rcpf(1.0f + __expf(-x));
}
__device__ __forceinline__ float tanh_(float x) {
    return 1.0f - 2.0f * __builtin_amdgcn_rcpf(__expf(2.0f * x) + 1.0f);
}

// LDS-only barrier: drain own LDS ops, then workgroup barrier (no vmcnt drain).
__device__ __forceinline__ void lds_barrier() {
    asm volatile("s_waitcnt lgkmcnt(0)" ::: "memory");
    __builtin_amdgcn_s_barrier();
    asm volatile("" ::: "memory");
}

// ================= Phase 1: xp[d][t][b][g] = x[t]·W_ih_d^T + b_ih + b_hh (bf16) =====
__global__ __launch_bounds__(256) void xp_gemm(
    const float* __restrict__ x,
    const float* __restrict__ w_ih_f, const float* __restrict__ w_ih_b,
    const float* __restrict__ b_ih_f, const float* __restrict__ b_hh_f,
    const float* __restrict__ b_ih_b, const float* __restrict__ b_hh_b,
    unsigned short* __restrict__ xp)
{
    const int mt = blockIdx.x >> 5;
    const int dn = blockIdx.x & 31;
    const int d  = dn >> 4, nt = dn & 15;
    const int t  = mt >> 2, b0 = (mt & 3) * 64, Nb = nt * 64;
    const float* w_ih = d ? w_ih_b : w_ih_f;
    const float* b_ih = d ? b_ih_b : b_ih_f;
    const float* b_hh = d ? b_hh_b : b_hh_f;
    const int tid = threadIdx.x;

    __shared__ short xl[64][136];
    __shared__ short wl[64][136];

    #pragma unroll
    for (int j = 0; j < 8; ++j) {
        const int c2 = tid + j * 256;
        const int r = c2 >> 5, o4 = (c2 & 31) * 4;
        float4 xv = *(const float4*)(x + ((size_t)(t * NB + b0 + r)) * NIN + o4);
        s16x4 xs; xs[0] = f2bf(xv.x); xs[1] = f2bf(xv.y); xs[2] = f2bf(xv.z); xs[3] = f2bf(xv.w);
        *(s16x4*)&xl[r][o4] = xs;
        float4 wv = *(const float4*)(w_ih + ((size_t)(Nb + r)) * NIN + o4);
        s16x4 ws_; ws_[0] = f2bf(wv.x); ws_[1] = f2bf(wv.y); ws_[2] = f2bf(wv.z); ws_[3] = f2bf(wv.w);
        *(s16x4*)&wl[r][o4] = ws_;
    }
    __syncthreads();

    const int v = tid >> 6, l = tid & 63, lg = l >> 4, lb = l & 15;
    s16x8 a[4];
    #pragma unroll
    for (int kk = 0; kk < 4; ++kk)
        a[kk] = *(const s16x8*)&xl[16 * v + lb][kk * 32 + 8 * lg];
    f32x4 acc[4];
    #pragma unroll
    for (int nf = 0; nf < 4; ++nf) {
        const int g = Nb + nf * 16 + lb;
        const float bs = b_ih[g] + b_hh[g];
        acc[nf][0] = bs; acc[nf][1] = bs; acc[nf][2] = bs; acc[nf][3] = bs;
    }
    #pragma unroll
    for (int kk = 0; kk < 4; ++kk)
        #pragma unroll
        for (int nf = 0; nf < 4; ++nf) {
            s16x8 bf_ = *(const s16x8*)&wl[nf * 16 + lb][kk * 32 + 8 * lg];
            acc[nf] = __builtin_amdgcn_mfma_f32_16x16x32_bf16(a[kk], bf_, acc[nf], 0, 0, 0);
        }
    #pragma unroll
    for (int nf = 0; nf < 4; ++nf)
        #pragma unroll
        for (int rr = 0; rr < 4; ++rr) {
            const int b = b0 + 16 * v + 4 * lg + rr;
            xp[((size_t)(d * T_SEQ + t) * NB + b) * 1024 + Nb + nf * 16 + lb] =
                (unsigned short)f2bf(acc[nf][rr]);
        }
}

// ================= Phase 2: recurrence, i8 W_hh register-resident ==================
// Grid 256 = 2 dirs * 128 batch-tiles (2 rows) -> ALL 256 CUs. Block 1024
// (16 waves, 4/SIMD). Wave w owns hidden [16w,16w+16) for all 4 gates
// (wq[4][4] = 64 VGPRs, R13-identical). Per step:
//   phase 1 (all 16 waves): ds_read hl (linear, conflict-free) -> 16 MFMAs ->
//            lanes lb<2 write raw i32 accs to rs[G*2+col][hu]   | barrier A
//   phase 2 (waves 0-7 ONLY, full 64-lane): read rs -> ONE gate-set/thread ->
//            out store + h byte -> hl; xp prefetch                | barrier B
// Concentrating gates on 8 waves halves per-SIMD transcendental ISSUE (2
// trans-waves/SIMD) — exec-masked lanes wouldn't. Single hl buffer: gates
// overwrite h only after barrier A; next MFMA reads after barrier B.
__global__ __launch_bounds__(1024, 4) void lstm_rec(
    const float* __restrict__ w_hh_f, const float* __restrict__ w_hh_b,
    const unsigned short* __restrict__ xp, float* __restrict__ out)
{
    const int bid = blockIdx.x;
    const int d  = bid >> 7;
    const int bt = bid & 127;
    const float* w_hh = d ? w_hh_b : w_hh_f;
    const int tid = threadIdx.x;
    const int w = tid >> 6, l = tid & 63, lg = l >> 4, lb = l & 15;

    __shared__ int hl[1024];      // i8 h, linear B-layout, single buffer (4 KB)
    __shared__ int rs[8][256];    // [G*2+col][hu] raw i32 accs (8 KB)

    // ---- W_hh -> i8 A-fragments (lane: A[row=lb][k = 64*kk + 16*lg + e]) ----
    i32x4 wq[4][4];
    #pragma unroll
    for (int G = 0; G < 4; ++G) {
        const int row = G * 256 + 16 * w + lb;
        #pragma unroll
        for (int kk = 0; kk < 4; ++kk) {
            i32x4 pk;
            #pragma unroll
            for (int r = 0; r < 4; ++r) {
                float4 wv = *(const float4*)(w_hh + (size_t)row * NH + kk * 64 + 16 * lg + 4 * r);
                const int q0 = (int)rintf(wv.x * 2032.0f) & 255;
                const int q1 = (int)rintf(wv.y * 2032.0f) & 255;
                const int q2 = (int)rintf(wv.z * 2032.0f) & 255;
                const int q3 = (int)rintf(wv.w * 2032.0f) & 255;
                pk[r] = q0 | (q1 << 8) | (q2 << 16) | (q3 << 24);
            }
            wq[G][kk] = pk;
        }
    }
    hl[tid] = 0;   // h(0) = 0; cols 2..15 stay 0 forever

    // gate-thread constants (waves 0..7 only)
    const int gc  = l & 1;             // batch col within tile
    const int ghu = 32 * w + (l >> 1); // this thread's hidden unit (w < 8)
    signed char* hlbyte = (signed char*)hl
        + (ghu >> 6) * 1024 + ((ghu >> 4) & 3) * 256 + gc * 16 + (ghu & 15);

    float cst = 0.f;
    unsigned short X[4];
    const int t0 = d ? (T_SEQ - 1) : 0;
    const long dxp  = (d ? -(long)NB : (long)NB) * 1024;
    const long dout = (d ? -(long)NB : (long)NB) * 512;
    const unsigned short* xpp =
        xp + ((size_t)(d * T_SEQ + t0) * NB + bt * 2 + gc) * 1024 + ghu;
    float* outp = out + ((size_t)t0 * NB + bt * 2 + gc) * 512 + d * 256 + ghu;
    if (w < 8) {
        X[0] = xpp[0]; X[1] = xpp[256]; X[2] = xpp[512]; X[3] = xpp[768];
        xpp += dxp;
    }
    __syncthreads();

    for (int s = 0; s < T_SEQ; ++s) {
        // ---- phase 1: MFMAs on h(s); raw accs -> rs ----
        i32x4 ac[4];
        #pragma unroll
        for (int G = 0; G < 4; ++G) { ac[G][0] = 0; ac[G][1] = 0; ac[G][2] = 0; ac[G][3] = 0; }
        #pragma unroll
        for (int kk = 0; kk < 4; ++kk) {
            i32x4 bq = *(const i32x4*)&hl[kk * 256 + 4 * l];
            ac[0] = __builtin_amdgcn_mfma_i32_16x16x64_i8(wq[0][kk], bq, ac[0], 0, 0, 0);
            ac[1] = __builtin_amdgcn_mfma_i32_16x16x64_i8(wq[1][kk], bq, ac[1], 0, 0, 0);
            ac[2] = __builtin_amdgcn_mfma_i32_16x16x64_i8(wq[2][kk], bq, ac[2], 0, 0, 0);
            ac[3] = __builtin_amdgcn_mfma_i32_16x16x64_i8(wq[3][kk], bq, ac[3], 0, 0, 0);
        }
        if (lb < 2) {                       // real batch cols
            #pragma unroll
            for (int G = 0; G < 4; ++G)
                *(i32x4*)&rs[G * 2 + lb][16 * w + 4 * lg] = ac[G];
        }
        lds_barrier();                      // barrier A: rs ready; hl free to overwrite

        // ---- phase 2: gates on waves 0-7 (one real set per lane) ----
        if (w < 8) {
            const int a0 = rs[0 + gc][ghu];
            const int a1 = rs[2 + gc][ghu];
            const int a2 = rs[4 + gc][ghu];
            const int a3 = rs[6 + gc][ghu];
            const float gi = SCQ * (float)a0 + bf2f(X[0]);
            const float gf = SCQ * (float)a1 + bf2f(X[1]);
            const float gg = SCQ * (float)a2 + bf2f(X[2]);
            const float go = SCQ * (float)a3 + bf2f(X[3]);
            const float iv = sigf(gi), fv = sigf(gf);
            const float gv = tanh_(gg), ov = sigf(go);
            const float cc = fv * cst + iv * gv;
            cst = cc;
            const float h = ov * tanh_(cc);
            *outp = h;
            outp += dout;
            *hlbyte = (signed char)(int)rintf(h * 127.0f);
            // prefetch next step's xp (full step of latency slack; end-of-seq
            // overshoot lands in the other direction's region -> in-bounds)
            X[0] = xpp[0]; X[1] = xpp[256]; X[2] = xpp[512]; X[3] = xpp[768];
            xpp += dxp;
        }
        lds_barrier();                      // barrier B: h(s+1) visible to all
    }
}

// ================= Fallback (R3, 829 us): used only if ws too small ================
#define ZSTR_FB 392
__global__ __launch_bounds__(512, 2) void lstm_fb(
    const float* __restrict__ x,
    const float* __restrict__ w_ih_f, const float* __restrict__ w_hh_f,
    const float* __restrict__ b_ih_f, const float* __restrict__ b_hh_f,
    const float* __restrict__ w_ih_b, const float* __restrict__ w_hh_b,
    const float* __restrict__ b_ih_b, const float* __restrict__ b_hh_b,
    float* __restrict__ out, unsigned* __restrict__ flags)
{
    const int b  = blockIdx.x;
    const int d  = b >> 5;
    const int hh = (b >> 4) & 1;
    const int bt = b & 15;
    const int pb = b ^ 16;
    const int po = 1 - hh;
    const float* w_ih = d ? w_ih_b : w_ih_f;
    const float* w_hh = d ? w_hh_b : w_hh_f;
    const float* b_ih = d ? b_ih_b : b_ih_f;
    const float* b_hh = d ? b_hh_b : b_hh_f;
    const int tid = threadIdx.x;
    const int w = tid >> 6, l = tid & 63, lg = l >> 4, lb = l & 15;
    const int hbase = hh * 128 + 16 * w;

    __shared__ short Z[2][16][ZSTR_FB];
    __shared__ float biasL[8][4][16];
    const int off_x   = lg * 8;
    const int off_own = (4 + 4 * hh) * 32 + lg * 8;
    const int off_par = (4 + 4 * po) * 32 + lg * 8;

    s16x8 wf[4][12];
    #pragma unroll
    for (int G = 0; G < 4; ++G) {
        const int gc = G * 256 + hbase + lb;
        #pragma unroll
        for (int kkidx = 0; kkidx < 12; ++kkidx) {
            const int kb = (kkidx < 4) ? (off_x + 32 * kkidx)
                         : (kkidx < 8) ? (off_own + 32 * (kkidx - 4))
                                       : (off_par + 32 * (kkidx - 8));
            const float* src = (kb < NIN) ? (w_ih + (size_t)gc * NIN + kb)
                                          : (w_hh + (size_t)gc * NH + (kb - NIN));
            float4 a  = *(const float4*)(src);
            float4 b2 = *(const float4*)(src + 4);
            s16x8 tv;
            tv[0] = f2bf(a.x);  tv[1] = f2bf(a.y);  tv[2] = f2bf(a.z);  tv[3] = f2bf(a.w);
            tv[4] = f2bf(b2.x); tv[5] = f2bf(b2.y); tv[6] = f2bf(b2.z); tv[7] = f2bf(b2.w);
            wf[G][kkidx] = tv;
        }
    }
    {
        const int G = lb >> 2, r = lb & 3;
        const int gcr = G * 256 + hbase + 4 * lg + r;
        biasL[w][G][4 * lg + r] = b_ih[gcr] + b_hh[gcr];
    }
    const int srow = tid >> 5;
    const int sk4  = (tid & 31) * 4;
    {
        s16x8 zz;
        #pragma unroll
        for (int i = 0; i < 8; ++i) zz[i] = 0;
        *(s16x8*)&Z[0][srow][NIN + (tid & 31) * 8] = zz;
        const int t0 = d ? (T_SEQ - 1) : 0;
        float4 xv0 = *(const float4*)(x + ((size_t)(t0 * NB + bt * 16 + srow)) * NIN + sk4);
        s16x4 xp_;
        xp_[0] = f2bf(xv0.x); xp_[1] = f2bf(xv0.y); xp_[2] = f2bf(xv0.z); xp_[3] = f2bf(xv0.w);
        *(s16x4*)&Z[0][srow][sk4] = xp_;
    }
    float cst[4] = {0.f, 0.f, 0.f, 0.f};
    __syncthreads();
    unsigned* myflag = flags + b * 16;
    unsigned* pflag  = flags + pb * 16;
    float* outp = out + (size_t)(bt * 16) * 512 + d * 256 + hbase + 4 * lg;

    for (int s = 0; s < T_SEQ; ++s) {
        const int p = s & 1;
        const int t = d ? (T_SEQ - 1 - s) : s;
        float4 xv;
        const bool havex = (s + 1 < T_SEQ);
        if (havex) {
            const int tn = d ? (T_SEQ - 2 - s) : (s + 1);
            xv = *(const float4*)(x + ((size_t)(tn * NB + bt * 16 + srow)) * NIN + sk4);
        }
        f32x4 acc[4];
        #pragma unroll
        for (int G = 0; G < 4; ++G)
            acc[G] = *(const f32x4*)&biasL[w][G][4 * lg];
        const short* zrow = &Z[p][lb][0];
        #pragma unroll
        for (int kk = 0; kk < 4; ++kk) {
            s16x8 bfv = *(const s16x8*)(zrow + off_x + 32 * kk);
            acc[0] = __builtin_amdgcn_mfma_f32_16x16x32_bf16(wf[0][kk], bfv, acc[0], 0, 0, 0);
            acc[1] = __builtin_amdgcn_mfma_f32_16x16x32_bf16(wf[1][kk], bfv, acc[1], 0, 0, 0);
            acc[2] = __builtin_amdgcn_mfma_f32_16x16x32_bf16(wf[2][kk], bfv, acc[2], 0, 0, 0);
            acc[3] = __builtin_amdgcn_mfma_f32_16x16x32_bf16(wf[3][kk], bfv, acc[3], 0, 0, 0);
        }
        #pragma unroll
        for (int kk = 0; kk < 4; ++kk) {
            s16x8 bfv = *(const s16x8*)(zrow + off_own + 32 * kk);
            acc[0] = __builtin_amdgcn_mfma_f32_16x16x32_bf16(wf[0][4 + kk], bfv, acc[0], 0, 0, 0);
            acc[1] = __builtin_amdgcn_mfma_f32_16x16x32_bf16(wf[1][4 + kk], bfv, acc[1], 0, 0, 0);
            acc[2] = __builtin_amdgcn_mfma_f32_16x16x32_bf16(wf[2][4 + kk], bfv, acc[2], 0, 0, 0);
            acc[3] = __builtin_amdgcn_mfma_f32_16x16x32_bf16(wf[3][4 + kk], bfv, acc[3], 0, 0, 0);
        }
        if (s > 0) {
            const unsigned want = (unsigned)s;
            while (__hip_atomic_load(pflag, __ATOMIC_RELAXED, __HIP_MEMORY_SCOPE_AGENT) < want)
                __builtin_amdgcn_s_sleep(1);
            __builtin_amdgcn_fence(__ATOMIC_ACQUIRE, "agent");
            const int tprev = d ? (T_SEQ - s) : (s - 1);
            float4 pv = *(const float4*)(out + (size_t)tprev * NB * 512
                         + (size_t)(bt * 16 + srow) * 512 + d * 256 + po * 128 + sk4);
            s16x4 pp;
            pp[0] = f2bf(pv.x); pp[1] = f2bf(pv.y); pp[2] = f2bf(pv.z); pp[3] = f2bf(pv.w);
            *(s16x4*)&Z[p][srow][NIN + po * 128 + sk4] = pp;
        }
        __syncthreads();
        #pragma unroll
        for (int kk = 0; kk < 4; ++kk) {
            s16x8 bfv = *(const s16x8*)(zrow + off_par + 32 * kk);
            acc[0] = __builtin_amdgcn_mfma_f32_16x16x32_bf16(wf[0][8 + kk], bfv, acc[0], 0, 0, 0);
            acc[1] = __builtin_amdgcn_mfma_f32_16x16x32_bf16(wf[1][8 + kk], bfv, acc[1], 0, 0, 0);
            acc[2] = __builtin_amdgcn_mfma_f32_16x16x32_bf16(wf[2][8 + kk], bfv, acc[2], 0, 0, 0);
            acc[3] = __builtin_amdgcn_mfma_f32_16x16x32_bf16(wf[3][8 + kk], bfv, acc[3], 0, 0, 0);
        }
        float4 hout; s16x4 hbf;
        #pragma unroll
        for (int r = 0; r < 4; ++r) {
            const float iv = sigf(acc[0][r]);
            const float fv = sigf(acc[1][r]);
            const float gv = tanh_(acc[2][r]);
            const float ov = sigf(acc[3][r]);
            const float cc = fv * cst[r] + iv * gv;
            cst[r] = cc;
            const float h = ov * tanh_(cc);
            (&hout.x)[r] = h;
            hbf[r] = f2bf(h);
        }
        *(s16x4*)&Z[p ^ 1][lb][NIN + hbase + 4 * lg] = hbf;
        if (havex) {
            s16x4 xp_;
            xp_[0] = f2bf(xv.x); xp_[1] = f2bf(xv.y); xp_[2] = f2bf(xv.z); xp_[3] = f2bf(xv.w);
            *(s16x4*)&Z[p ^ 1][srow][sk4] = xp_;
        }
        *(f32x4*)(outp + (size_t)t * NB * 512 + lb * 512) = *(f32x4*)&hout;
        __syncthreads();
        if (tid == 0 && s + 1 < T_SEQ)
            __hip_atomic_store(myflag, (unsigned)(s + 1),
                               __ATOMIC_RELEASE, __HIP_MEMORY_SCOPE_AGENT);
    }
}

extern "C" void kernel_launch(void* const* d_in, const int* in_sizes, int n_in,
                              void* d_out, int out_size, void* d_ws, size_t ws_size,
                              hipStream_t stream) {
    const float* x      = (const float*)d_in[0];
    const float* w_ih_f = (const float*)d_in[1];
    const float* w_hh_f = (const float*)d_in[2];
    const float* b_ih_f = (const float*)d_in[3];
    const float* b_hh_f = (const float*)d_in[4];
    const float* w_ih_b = (const float*)d_in[5];
    const float* w_hh_b = (const float*)d_in[6];
    const float* b_ih_b = (const float*)d_in[7];
    const float* b_hh_b = (const float*)d_in[8];
    float* out = (float*)d_out;

    const size_t XPN = (size_t)2 * T_SEQ * NB * 1024;   // elements
    const int g1 = (T_SEQ * NB / 64) * 32;              // 24064 WGs

    if (ws_size >= XPN * 2) {
        unsigned short* xp = (unsigned short*)d_ws;
        xp_gemm<<<dim3(g1), dim3(256), 0, stream>>>(
            x, w_ih_f, w_ih_b, b_ih_f, b_hh_f, b_ih_b, b_hh_b, xp);
        lstm_rec<<<dim3(256), dim3(1024), 0, stream>>>(w_hh_f, w_hh_b, xp, out);
    } else {
        unsigned* flags = (unsigned*)d_ws;
        hipMemsetAsync(flags, 0, 4096, stream);
        lstm_fb<<<dim3(64), dim3(512), 0, stream>>>(
            x, w_ih_f, w_hh_f, b_ih_f, b_hh_f, w_ih_b, w_hh_b, b_ih_b, b_hh_b,
            out, flags);
    }
}

// Round 16
// 346.298 us; speedup vs baseline: 1.3742x; 1.2402x over previous
//
#include <hip/hip_runtime.h>

#define T_SEQ 188
#define NB    256
#define NIN   128
#define NH    256
#define SCQ   (0.0625f / 16129.0f)   // (0.0625/127) * (1/127)

typedef __attribute__((ext_vector_type(8))) short s16x8;
typedef __attribute__((ext_vector_type(4))) short s16x4;
typedef __attribute__((ext_vector_type(4))) float f32x4;
typedef __attribute__((ext_vector_type(4))) int   i32x4;

__device__ __forceinline__ short f2bf(float f) {
    union { float f; unsigned u; } v; v.f = f;
    unsigned r = v.u + 0x7fffu + ((v.u >> 16) & 1u);   // RNE
    return (short)(r >> 16);
}
__device__ __forceinline__ float bf2f(unsigned short s) {
    union { unsigned u; float f; } t; t.u = ((unsigned)s) << 16; return t.f;
}
__device__ __forceinline__ float sigf(float x) {
    return __builtin_amdgcn_rcpf(1.0f + __expf(-x));
}
__device__ __forceinline__ float tanh_(float x) {
    return 1.0f - 2.0f * __builtin_amdgcn_rcpf(__expf(2.0f * x) + 1.0f);
}

// LDS-only barrier: drain own LDS ops, then workgroup barrier (no vmcnt drain).
__device__ __forceinline__ void lds_barrier() {
    asm volatile("s_waitcnt lgkmcnt(0)" ::: "memory");
    __builtin_amdgcn_s_barrier();
    asm volatile("" ::: "memory");
}

// ===== Phase 1: xp[d][t][b][g] = x[t]·W_ih_d^T + b_ih + b_hh (bf16 out) ==========
// One WG = M=64 rows x FULL N=1024: x A-frags live in REGISTERS (loaded once,
// straight from global — no x re-staging per N-group; was 1.57 GB of L2/IC
// traffic at 64x64 tiles). W streams through a 17 KB LDS tile, 16 iterations.
// Grid 1504 = 752 M-tiles x 2 dirs. Block 256 (4 waves; wave v owns rows 16v..).
__global__ __launch_bounds__(256) void xp_gemm(
    const float* __restrict__ x,
    const float* __restrict__ w_ih_f, const float* __restrict__ w_ih_b,
    const float* __restrict__ b_ih_f, const float* __restrict__ b_hh_f,
    const float* __restrict__ b_ih_b, const float* __restrict__ b_hh_b,
    unsigned short* __restrict__ xp)
{
    const int mt = blockIdx.x >> 1;
    const int d  = blockIdx.x & 1;
    const int t  = mt >> 2, b0 = (mt & 3) * 64;
    const float* w_ih = d ? w_ih_b : w_ih_f;
    const float* b_ih = d ? b_ih_b : b_ih_f;
    const float* b_hh = d ? b_hh_b : b_hh_f;
    const int tid = threadIdx.x;
    const int v = tid >> 6, l = tid & 63, lg = l >> 4, lb = l & 15;

    __shared__ short wl[64][136];     // W tile, padded (2-way banks on b128 reads)
    __shared__ float biasS[1024];     // b_ih + b_hh sums

    #pragma unroll
    for (int j = 0; j < 4; ++j) {
        const int g = tid * 4 + j * 1024; (void)g;
    }
    {
        const int g = tid * 4;
        float4 bi = *(const float4*)(b_ih + g);
        float4 bh = *(const float4*)(b_hh + g);
        biasS[g + 0] = bi.x + bh.x; biasS[g + 1] = bi.y + bh.y;
        biasS[g + 2] = bi.z + bh.z; biasS[g + 3] = bi.w + bh.w;
    }

    // ---- x A-fragments -> registers (once): lane holds A[16v+lb][32kk+8lg+e]
    s16x8 a[4];
    {
        const float* xr = x + ((size_t)(t * NB + b0 + 16 * v + lb)) * NIN + 8 * lg;
        #pragma unroll
        for (int kk = 0; kk < 4; ++kk) {
            float4 p0 = *(const float4*)(xr + 32 * kk);
            float4 p1 = *(const float4*)(xr + 32 * kk + 4);
            s16x8 tv;
            tv[0] = f2bf(p0.x); tv[1] = f2bf(p0.y); tv[2] = f2bf(p0.z); tv[3] = f2bf(p0.w);
            tv[4] = f2bf(p1.x); tv[5] = f2bf(p1.y); tv[6] = f2bf(p1.z); tv[7] = f2bf(p1.w);
            a[kk] = tv;
        }
    }

    // W staging assignment: thread stages row r = tid>>2, k-range (tid&3)*32..+31
    const int wr = tid >> 2, wk = (tid & 3) * 32;

    unsigned short* xpb =
        xp + ((size_t)(d * T_SEQ + t) * NB + b0 + 16 * v + 4 * lg) * 1024 + lb;

    for (int nt = 0; nt < 16; ++nt) {
        const int Nb = nt * 64;
        // ---- stage W tile (64 rows x 128 k) f32 -> bf16 LDS
        {
            const float* wsrc = w_ih + ((size_t)(Nb + wr)) * NIN + wk;
            #pragma unroll
            for (int j = 0; j < 4; ++j) {
                float4 p0 = *(const float4*)(wsrc + 8 * j);
                float4 p1 = *(const float4*)(wsrc + 8 * j + 4);
                s16x8 tv;
                tv[0] = f2bf(p0.x); tv[1] = f2bf(p0.y); tv[2] = f2bf(p0.z); tv[3] = f2bf(p0.w);
                tv[4] = f2bf(p1.x); tv[5] = f2bf(p1.y); tv[6] = f2bf(p1.z); tv[7] = f2bf(p1.w);
                *(s16x8*)&wl[wr][wk + 8 * j] = tv;
            }
        }
        __syncthreads();

        // ---- MFMA: 4 N-frags x 4 K-tiles, acc init from bias
        f32x4 acc[4];
        #pragma unroll
        for (int nf = 0; nf < 4; ++nf) {
            const float bs = biasS[Nb + nf * 16 + lb];
            acc[nf][0] = bs; acc[nf][1] = bs; acc[nf][2] = bs; acc[nf][3] = bs;
        }
        #pragma unroll
        for (int kk = 0; kk < 4; ++kk)
            #pragma unroll
            for (int nf = 0; nf < 4; ++nf) {
                s16x8 bf_ = *(const s16x8*)&wl[nf * 16 + lb][kk * 32 + 8 * lg];
                acc[nf] = __builtin_amdgcn_mfma_f32_16x16x32_bf16(a[kk], bf_, acc[nf], 0, 0, 0);
            }
        __syncthreads();   // wl reads done; safe to restage next iter

        // ---- store (D: row=4lg+rr -> batch, col=lb -> gate)
        #pragma unroll
        for (int nf = 0; nf < 4; ++nf)
            #pragma unroll
            for (int rr = 0; rr < 4; ++rr)
                xpb[(size_t)rr * 1024 + Nb + nf * 16] = (unsigned short)f2bf(acc[nf][rr]);
    }
}

// ================= Phase 2: recurrence (R13 structure, proven 236 us) =============
// Grid 128 = 2 dirs * 64 batch-tiles (4 rows), block 1024 (16 waves, 4 w/SIMD).
// hl: linear B-layout, conflict-free ds_read_b128. One lds_barrier per step.
__device__ __forceinline__ void lstm_step(
    int p, int w, int l, int lg, int lb, int c, int huq, int hwb,
    const unsigned short*& xpp, long dxp, float*& outp, long dout,
    int* hl, int (&rscr)[16][4][4][16],
    const i32x4 (&wq)[4][4], float& cst,
    unsigned short (&cur)[4], unsigned short (&nxt)[4])
{
    #pragma unroll
    for (int G = 0; G < 4; ++G)
        nxt[G] = xpp[G * 256];
    xpp += dxp;

    i32x4 ac[4];
    #pragma unroll
    for (int G = 0; G < 4; ++G) {
        ac[G][0] = 0; ac[G][1] = 0; ac[G][2] = 0; ac[G][3] = 0;
    }
    #pragma unroll
    for (int kk = 0; kk < 4; ++kk) {
        i32x4 bq = *(const i32x4*)&hl[p * 1024 + kk * 256 + 4 * l];
        ac[0] = __builtin_amdgcn_mfma_i32_16x16x64_i8(wq[0][kk], bq, ac[0], 0, 0, 0);
        ac[1] = __builtin_amdgcn_mfma_i32_16x16x64_i8(wq[1][kk], bq, ac[1], 0, 0, 0);
        ac[2] = __builtin_amdgcn_mfma_i32_16x16x64_i8(wq[2][kk], bq, ac[2], 0, 0, 0);
        ac[3] = __builtin_amdgcn_mfma_i32_16x16x64_i8(wq[3][kk], bq, ac[3], 0, 0, 0);
    }

    if (lb < 4) {
        #pragma unroll
        for (int G = 0; G < 4; ++G)
            *(i32x4*)&rscr[w][G][lb][4 * lg] = ac[G];
    }
    asm volatile("s_waitcnt lgkmcnt(0)" ::: "memory");
    int av[4];
    #pragma unroll
    for (int G = 0; G < 4; ++G)
        av[G] = rscr[w][G][c][huq];
    asm volatile("s_waitcnt lgkmcnt(0)" ::: "memory");

    const float gi = SCQ * (float)av[0] + bf2f(cur[0]);
    const float gf = SCQ * (float)av[1] + bf2f(cur[1]);
    const float gg = SCQ * (float)av[2] + bf2f(cur[2]);
    const float go = SCQ * (float)av[3] + bf2f(cur[3]);
    const float iv = sigf(gi), fv = sigf(gf);
    const float gv = tanh_(gg), ov = sigf(go);
    const float cc = fv * cst + iv * gv;
    cst = cc;
    const float h = ov * tanh_(cc);
    *outp = h;
    outp += dout;
    ((signed char*)hl)[(p ^ 1) * 4096 + hwb] = (signed char)(int)rintf(h * 127.0f);

    lds_barrier();
}

__global__ __launch_bounds__(1024, 4) void lstm_rec(
    const float* __restrict__ w_hh_f, const float* __restrict__ w_hh_b,
    const unsigned short* __restrict__ xp, float* __restrict__ out)
{
    const int bid = blockIdx.x;
    const int d  = bid >> 6;
    const int bt = bid & 63;
    const float* w_hh = d ? w_hh_b : w_hh_f;
    const int tid = threadIdx.x;
    const int w = tid >> 6, l = tid & 63, lg = l >> 4, lb = l & 15;
    const int c = l & 3, huq = l >> 2;

    __shared__ int hl[2 * 1024];         // i8 h, linear-read layout (8 KB)
    __shared__ int rscr[16][4][4][16];   // [wave][gate][col][hu] - wave-private

    i32x4 wq[4][4];
    #pragma unroll
    for (int G = 0; G < 4; ++G) {
        const int row = G * 256 + 16 * w + lb;
        #pragma unroll
        for (int kk = 0; kk < 4; ++kk) {
            i32x4 pk;
            #pragma unroll
            for (int r = 0; r < 4; ++r) {
                float4 wv = *(const float4*)(w_hh + (size_t)row * NH + kk * 64 + 16 * lg + 4 * r);
                const int q0 = (int)rintf(wv.x * 2032.0f) & 255;
                const int q1 = (int)rintf(wv.y * 2032.0f) & 255;
                const int q2 = (int)rintf(wv.z * 2032.0f) & 255;
                const int q3 = (int)rintf(wv.w * 2032.0f) & 255;
                pk[r] = q0 | (q1 << 8) | (q2 << 16) | (q3 << 24);
            }
            wq[G][kk] = pk;
        }
    }
    for (int i = tid; i < 2048; i += 1024) hl[i] = 0;   // h(0) = 0, both buffers

    const int hu = 16 * w + huq;
    const int hwb = (hu >> 6) * 1024 + ((hu >> 4) & 3) * 256 + c * 16 + (hu & 15);

    float cst = 0.f;
    unsigned short XPA[4], XPB[4];
    const int t0 = d ? (T_SEQ - 1) : 0;
    const long dxp  = (d ? -(long)NB : (long)NB) * 1024;
    const long dout = (d ? -(long)NB : (long)NB) * 512;
    const unsigned short* xpp =
        xp + ((size_t)(d * T_SEQ + t0) * NB + bt * 4 + c) * 1024 + hu;
    float* outp = out + ((size_t)t0 * NB + bt * 4 + c) * 512 + d * 256 + hu;
    #pragma unroll
    for (int G = 0; G < 4; ++G)
        XPA[G] = xpp[G * 256];
    xpp += dxp;
    __syncthreads();

    for (int s2 = 0; s2 < T_SEQ / 2; ++s2) {
        lstm_step(0, w, l, lg, lb, c, huq, hwb, xpp, dxp, outp, dout,
                  hl, rscr, wq, cst, XPA, XPB);
        lstm_step(1, w, l, lg, lb, c, huq, hwb, xpp, dxp, outp, dout,
                  hl, rscr, wq, cst, XPB, XPA);
    }
}

// ================= Fallback (R3, 829 us): used only if ws too small ================
#define ZSTR_FB 392
__global__ __launch_bounds__(512, 2) void lstm_fb(
    const float* __restrict__ x,
    const float* __restrict__ w_ih_f, const float* __restrict__ w_hh_f,
    const float* __restrict__ b_ih_f, const float* __restrict__ b_hh_f,
    const float* __restrict__ w_ih_b, const float* __restrict__ w_hh_b,
    const float* __restrict__ b_ih_b, const float* __restrict__ b_hh_b,
    float* __restrict__ out, unsigned* __restrict__ flags)
{
    const int b  = blockIdx.x;
    const int d  = b >> 5;
    const int hh = (b >> 4) & 1;
    const int bt = b & 15;
    const int pb = b ^ 16;
    const int po = 1 - hh;
    const float* w_ih = d ? w_ih_b : w_ih_f;
    const float* w_hh = d ? w_hh_b : w_hh_f;
    const float* b_ih = d ? b_ih_b : b_ih_f;
    const float* b_hh = d ? b_hh_b : b_hh_f;
    const int tid = threadIdx.x;
    const int w = tid >> 6, l = tid & 63, lg = l >> 4, lb = l & 15;
    const int hbase = hh * 128 + 16 * w;

    __shared__ short Z[2][16][ZSTR_FB];
    __shared__ float biasL[8][4][16];
    const int off_x   = lg * 8;
    const int off_own = (4 + 4 * hh) * 32 + lg * 8;
    const int off_par = (4 + 4 * po) * 32 + lg * 8;

    s16x8 wf[4][12];
    #pragma unroll
    for (int G = 0; G < 4; ++G) {
        const int gc = G * 256 + hbase + lb;
        #pragma unroll
        for (int kkidx = 0; kkidx < 12; ++kkidx) {
            const int kb = (kkidx < 4) ? (off_x + 32 * kkidx)
                         : (kkidx < 8) ? (off_own + 32 * (kkidx - 4))
                                       : (off_par + 32 * (kkidx - 8));
            const float* src = (kb < NIN) ? (w_ih + (size_t)gc * NIN + kb)
                                          : (w_hh + (size_t)gc * NH + (kb - NIN));
            float4 a  = *(const float4*)(src);
            float4 b2 = *(const float4*)(src + 4);
            s16x8 tv;
            tv[0] = f2bf(a.x);  tv[1] = f2bf(a.y);  tv[2] = f2bf(a.z);  tv[3] = f2bf(a.w);
            tv[4] = f2bf(b2.x); tv[5] = f2bf(b2.y); tv[6] = f2bf(b2.z); tv[7] = f2bf(b2.w);
            wf[G][kkidx] = tv;
        }
    }
    {
        const int G = lb >> 2, r = lb & 3;
        const int gcr = G * 256 + hbase + 4 * lg + r;
        biasL[w][G][4 * lg + r] = b_ih[gcr] + b_hh[gcr];
    }
    const int srow = tid >> 5;
    const int sk4  = (tid & 31) * 4;
    {
        s16x8 zz;
        #pragma unroll
        for (int i = 0; i < 8; ++i) zz[i] = 0;
        *(s16x8*)&Z[0][srow][NIN + (tid & 31) * 8] = zz;
        const int t0 = d ? (T_SEQ - 1) : 0;
        float4 xv0 = *(const float4*)(x + ((size_t)(t0 * NB + bt * 16 + srow)) * NIN + sk4);
        s16x4 xp_;
        xp_[0] = f2bf(xv0.x); xp_[1] = f2bf(xv0.y); xp_[2] = f2bf(xv0.z); xp_[3] = f2bf(xv0.w);
        *(s16x4*)&Z[0][srow][sk4] = xp_;
    }
    float cst[4] = {0.f, 0.f, 0.f, 0.f};
    __syncthreads();
    unsigned* myflag = flags + b * 16;
    unsigned* pflag  = flags + pb * 16;
    float* outp = out + (size_t)(bt * 16) * 512 + d * 256 + hbase + 4 * lg;

    for (int s = 0; s < T_SEQ; ++s) {
        const int p = s & 1;
        const int t = d ? (T_SEQ - 1 - s) : s;
        float4 xv;
        const bool havex = (s + 1 < T_SEQ);
        if (havex) {
            const int tn = d ? (T_SEQ - 2 - s) : (s + 1);
            xv = *(const float4*)(x + ((size_t)(tn * NB + bt * 16 + srow)) * NIN + sk4);
        }
        f32x4 acc[4];
        #pragma unroll
        for (int G = 0; G < 4; ++G)
            acc[G] = *(const f32x4*)&biasL[w][G][4 * lg];
        const short* zrow = &Z[p][lb][0];
        #pragma unroll
        for (int kk = 0; kk < 4; ++kk) {
            s16x8 bfv = *(const s16x8*)(zrow + off_x + 32 * kk);
            acc[0] = __builtin_amdgcn_mfma_f32_16x16x32_bf16(wf[0][kk], bfv, acc[0], 0, 0, 0);
            acc[1] = __builtin_amdgcn_mfma_f32_16x16x32_bf16(wf[1][kk], bfv, acc[1], 0, 0, 0);
            acc[2] = __builtin_amdgcn_mfma_f32_16x16x32_bf16(wf[2][kk], bfv, acc[2], 0, 0, 0);
            acc[3] = __builtin_amdgcn_mfma_f32_16x16x32_bf16(wf[3][kk], bfv, acc[3], 0, 0, 0);
        }
        #pragma unroll
        for (int kk = 0; kk < 4; ++kk) {
            s16x8 bfv = *(const s16x8*)(zrow + off_own + 32 * kk);
            acc[0] = __builtin_amdgcn_mfma_f32_16x16x32_bf16(wf[0][4 + kk], bfv, acc[0], 0, 0, 0);
            acc[1] = __builtin_amdgcn_mfma_f32_16x16x32_bf16(wf[1][4 + kk], bfv, acc[1], 0, 0, 0);
            acc[2] = __builtin_amdgcn_mfma_f32_16x16x32_bf16(wf[2][4 + kk], bfv, acc[2], 0, 0, 0);
            acc[3] = __builtin_amdgcn_mfma_f32_16x16x32_bf16(wf[3][4 + kk], bfv, acc[3], 0, 0, 0);
        }
        if (s > 0) {
            const unsigned want = (unsigned)s;
            while (__hip_atomic_load(pflag, __ATOMIC_RELAXED, __HIP_MEMORY_SCOPE_AGENT) < want)
                __builtin_amdgcn_s_sleep(1);
            __builtin_amdgcn_fence(__ATOMIC_ACQUIRE, "agent");
            const int tprev = d ? (T_SEQ - s) : (s - 1);
            float4 pv = *(const float4*)(out + (size_t)tprev * NB * 512
                         + (size_t)(bt * 16 + srow) * 512 + d * 256 + po * 128 + sk4);
            s16x4 pp;
            pp[0] = f2bf(pv.x); pp[1] = f2bf(pv.y); pp[2] = f2bf(pv.z); pp[3] = f2bf(pv.w);
            *(s16x4*)&Z[p][srow][NIN + po * 128 + sk4] = pp;
        }
        __syncthreads();
        #pragma unroll
        for (int kk = 0; kk < 4; ++kk) {
            s16x8 bfv = *(const s16x8*)(zrow + off_par + 32 * kk);
            acc[0] = __builtin_amdgcn_mfma_f32_16x16x32_bf16(wf[0][8 + kk], bfv, acc[0], 0, 0, 0);
            acc[1] = __builtin_amdgcn_mfma_f32_16x16x32_bf16(wf[1][8 + kk], bfv, acc[1], 0, 0, 0);
            acc[2] = __builtin_amdgcn_mfma_f32_16x16x32_bf16(wf[2][8 + kk], bfv, acc[2], 0, 0, 0);
            acc[3] = __builtin_amdgcn_mfma_f32_16x16x32_bf16(wf[3][8 + kk], bfv, acc[3], 0, 0, 0);
        }
        float4 hout; s16x4 hbf;
        #pragma unroll
        for (int r = 0; r < 4; ++r) {
            const float iv = sigf(acc[0][r]);
            const float fv = sigf(acc[1][r]);
            const float gv = tanh_(acc[2][r]);
            const float ov = sigf(acc[3][r]);
            const float cc = fv * cst[r] + iv * gv;
            cst[r] = cc;
            const float h = ov * tanh_(cc);
            (&hout.x)[r] = h;
            hbf[r] = f2bf(h);
        }
        *(s16x4*)&Z[p ^ 1][lb][NIN + hbase + 4 * lg] = hbf;
        if (havex) {
            s16x4 xp_;
            xp_[0] = f2bf(xv.x); xp_[1] = f2bf(xv.y); xp_[2] = f2bf(xv.z); xp_[3] = f2bf(xv.w);
            *(s16x4*)&Z[p ^ 1][srow][sk4] = xp_;
        }
        *(f32x4*)(outp + (size_t)t * NB * 512 + lb * 512) = *(f32x4*)&hout;
        __syncthreads();
        if (tid == 0 && s + 1 < T_SEQ)
            __hip_atomic_store(myflag, (unsigned)(s + 1),
                               __ATOMIC_RELEASE, __HIP_MEMORY_SCOPE_AGENT);
    }
}

extern "C" void kernel_launch(void* const* d_in, const int* in_sizes, int n_in,
                              void* d_out, int out_size, void* d_ws, size_t ws_size,
                              hipStream_t stream) {
    const float* x      = (const float*)d_in[0];
    const float* w_ih_f = (const float*)d_in[1];
    const float* w_hh_f = (const float*)d_in[2];
    const float* b_ih_f = (const float*)d_in[3];
    const float* b_hh_f = (const float*)d_in[4];
    const float* w_ih_b = (const float*)d_in[5];
    const float* w_hh_b = (const float*)d_in[6];
    const float* b_ih_b = (const float*)d_in[7];
    const float* b_hh_b = (const float*)d_in[8];
    float* out = (float*)d_out;

    const size_t XPN = (size_t)2 * T_SEQ * NB * 1024;   // elements

    if (ws_size >= XPN * 2) {
        unsigned short* xp = (unsigned short*)d_ws;
        xp_gemm<<<dim3(752 * 2), dim3(256), 0, stream>>>(
            x, w_ih_f, w_ih_b, b_ih_f, b_hh_f, b_ih_b, b_hh_b, xp);
        lstm_rec<<<dim3(128), dim3(1024), 0, stream>>>(w_hh_f, w_hh_b, xp, out);
    } else {
        unsigned* flags = (unsigned*)d_ws;
        hipMemsetAsync(flags, 0, 4096, stream);
        lstm_fb<<<dim3(64), dim3(512), 0, stream>>>(
            x, w_ih_f, w_hh_f, b_ih_f, b_hh_f, w_ih_b, w_hh_b, b_ih_b, b_hh_b,
            out, flags);
    }
}